// Round 1
// 9.843 us; speedup vs baseline: 4.1176x; 4.1176x over previous
//
#include <hip/hip_runtime.h>

// Closed-form Pauli contraction replacing the 512-amplitude statevector sim.
//
// Frame (inherited from the verified statevector kernel): after folding the
// layer-1 CNOTs into a GF(2) index remap, |psi> is a PRODUCT state over 9
// physical bits (bit m holds qubit q = 8-m; per-bit 2-vector
// b = Rot1_q * RX_q |0>), and the conjugated observable is
//   O = prod_{p in {8,7,5,3,1}} h^(p),
//   h^(p) = al_p Z_{u_p} + br_p X_{w_p} + i bi_p Z_{u_p} X_{w_p}
// with 9-bit physical masks
//   p=8:(u=0x0FF,w=0x180) p=7:(0x180,0x0C0) p=5:(0x1E0,0x030)
//   p=3:(0x1F8,0x00C)     p=1:(0x1FE,0x003)
// Key facts: u_p . w_q = delta_pq (parity), u's and w's independent. Expanding
// O into 3^5 = 243 Pauli terms Z_U X_W picks per-p a trit c_p:
//   c=0: (a,b)=(1,0) coeff al;  c=1: (0,1) coeff br;  c=2: (1,1) coeff i*bi
// (no reordering signs since u_p.w_q = 0 for p != q). Product-state
// expectation factors over bits: <b|Z^u X^w|b> = 1 / z / x / i*y for
// (u,w) = 00/10/01/11, with per-bit Bloch components
//   z = |b0|^2-|b1|^2, x = 2 Re(conj(b0) b1), y = 2 Im(conj(b0) b1).
// Every complete term is real: popcount(U&W) == #(c=2) (mod 2).
//
// Per-bit (U_m, W_m) as functions of the choice bits (from the masks):
//   m=0:(a8, b1)  m=1:(t1, b1)  m=2:(t1, b3)  m=3:(t3, b3)  m=4:(t3, b5)
//   m=5:(t5, b5)  m=6:(t5, b7)  m=7:(t5^a7, b7^b8)  m=8:(t5^a8^a7, b8)
//   with t1 = a8^a1, t3 = t1^a3, t5 = t3^a5.
// This staircase gives a 4-level DP over (c7) -> (c5) -> (c3) -> (c1) with
// state (t, c8), complex arithmetic carrying the i's.
//
// Cost: ~1.5k lane-ops per sample vs ~78k lane-op-slots for the statevector
// version -> ONE THREAD PER SAMPLE (512 waves total for 32768 samples).
// DP hand-validated against all-Z, single-X and single-iZX parameter settings.

#if defined(__clang__)
#pragma float_control(precise, off)   // fold the structural 0/1 components
#endif

struct C2 { float r, i; };
__device__ __forceinline__ C2 cmul(C2 a, C2 b) {
    return C2{a.r * b.r - a.i * b.i, a.r * b.i + a.i * b.r};
}
__device__ __forceinline__ C2 cadd(C2 a, C2 b) { return C2{a.r + b.r, a.i + b.i}; }

__global__ __launch_bounds__(64) void qsim_kernel(const float* __restrict__ x,
                                                  const float* __restrict__ w,
                                                  float* __restrict__ out,
                                                  int nsamples) {
    __shared__ float rm[9][8];   // layer-1 Rot matrices (m00,m01,m10,m11 as r,i)
    __shared__ float hm[5][3];   // h params for p = 8,7,5,3,1: {alpha, beta_r, beta_i}
    const int tid = threadIdx.x;
    if (tid < 9) {
        const int q = tid;
        const float phi = w[q * 3 + 0], theta = w[q * 3 + 1], omega = w[q * 3 + 2];
        float st, ct, sp, cp, sm, cm;
        __sincosf(0.5f * theta, &st, &ct);
        __sincosf(0.5f * (phi + omega), &sp, &cp);
        __sincosf(0.5f * (phi - omega), &sm, &cm);
        float* m = rm[q];
        m[0] =  cp * ct; m[1] = -sp * ct;   // m00
        m[2] = -cm * st; m[3] = -sm * st;   // m01
        m[4] =  cm * st; m[5] = -sm * st;   // m10
        m[6] =  cp * ct; m[7] =  sp * ct;   // m11
    } else if (tid >= 16 && tid < 21) {
        const int i = tid - 16;
        const int qs[5] = {0, 1, 3, 5, 7};  // wire q; logical p = 8,7,5,3,1
        const int q = qs[i];
        const float phi = w[27 + q * 3 + 0], theta = w[27 + q * 3 + 1];
        float stt, ctt, sf, cf;
        __sincosf(theta, &stt, &ctt);
        __sincosf(phi, &sf, &cf);
        hm[i][0] = ctt;          // alpha = cos(theta)
        hm[i][1] = -stt * cf;    // beta  = -sin(theta) e^{i phi}
        hm[i][2] = -stt * sf;
    }
    __syncthreads();

    const int n = (blockIdx.x << 6) + tid;   // one sample per thread
    if (n >= nsamples) return;
    const int b  = n >> 12;
    const int i0 = (n >> 6) & 63;
    const int j0 = n & 63;                   // lane == column -> coalesced loads

    // --- per-qubit embedded+rotated 2-vectors (identical to verified kernel) ---
    float br0[9], bi0[9], br1[9], bi1[9];
    #pragma unroll
    for (int ki = 0; ki < 3; ++ki) {
        #pragma unroll
        for (int kj = 0; kj < 3; ++kj) {
            const int q = ki * 3 + kj;
            const int ii = i0 + ki - 1, jj = j0 + kj - 1;
            float a = 0.0f;
            if (ii >= 0 && ii < 64 && jj >= 0 && jj < 64)
                a = x[(b << 12) + (ii << 6) + jj];
            float s, c;
            __sincosf(0.5f * a, &s, &c);
            const float* m = rm[q];
            br0[q] = m[0] * c + m[3] * s;
            bi0[q] = m[1] * c - m[2] * s;
            br1[q] = m[4] * c + m[7] * s;
            bi1[q] = m[5] * c - m[6] * s;
        }
    }

    // --- Bloch components per physical bit m (qubit q = 8 - m) ---
    float Zb[9], Xb[9], Yb[9];
    #pragma unroll
    for (int m = 0; m < 9; ++m) {
        const int q = 8 - m;
        Zb[m] = (br0[q] * br0[q] + bi0[q] * bi0[q]) - (br1[q] * br1[q] + bi1[q] * bi1[q]);
        Xb[m] = 2.0f * (br0[q] * br1[q] + bi0[q] * bi1[q]);
        Yb[m] = 2.0f * (br0[q] * bi1[q] - bi0[q] * br1[q]);
    }

    // per-bit complex Pauli factors F[m][U][W]
    C2 F[9][2][2];
    #pragma unroll
    for (int m = 0; m < 9; ++m) {
        F[m][0][0] = C2{1.0f, 0.0f};
        F[m][1][0] = C2{Zb[m], 0.0f};
        F[m][0][1] = C2{Xb[m], 0.0f};
        F[m][1][1] = C2{0.0f, Yb[m]};
    }

    // choice coefficients: slot 0=p8, 1=p7, 2=p5, 3=p3, 4=p1 (hm order)
    C2 K[5][3];
    #pragma unroll
    for (int i = 0; i < 5; ++i) {
        K[i][0] = C2{hm[i][0], 0.0f};   // alpha  (Z)
        K[i][1] = C2{hm[i][1], 0.0f};   // br     (X)
        K[i][2] = C2{0.0f, hm[i][2]};   // i*bi   (ZX)
    }

    const int A[3] = {1, 0, 1};   // a_p per trit
    const int B[3] = {0, 1, 1};   // b_p per trit

    // ---- level 7: bits 6,7,8 ----
    C2 S7[2][3];
    #pragma unroll
    for (int t5 = 0; t5 < 2; ++t5) {
        #pragma unroll
        for (int c8 = 0; c8 < 3; ++c8) {
            const int a8 = A[c8], b8 = B[c8];
            C2 acc = C2{0.0f, 0.0f};
            #pragma unroll
            for (int c7 = 0; c7 < 3; ++c7) {
                const int a7 = A[c7], b7 = B[c7];
                C2 v = cmul(K[1][c7], F[6][t5][b7]);
                v = cmul(v, F[7][t5 ^ a7][b7 ^ b8]);
                v = cmul(v, F[8][t5 ^ a8 ^ a7][b8]);
                acc = cadd(acc, v);
            }
            S7[t5][c8] = acc;
        }
    }

    // ---- level 5: bits 4,5 ----
    C2 S5[2][3];
    #pragma unroll
    for (int t3 = 0; t3 < 2; ++t3) {
        #pragma unroll
        for (int c8 = 0; c8 < 3; ++c8) {
            C2 acc = C2{0.0f, 0.0f};
            #pragma unroll
            for (int c5 = 0; c5 < 3; ++c5) {
                const int a5 = A[c5], b5 = B[c5];
                C2 v = cmul(K[2][c5], F[4][t3][b5]);
                v = cmul(v, F[5][t3 ^ a5][b5]);
                v = cmul(v, S7[t3 ^ a5][c8]);
                acc = cadd(acc, v);
            }
            S5[t3][c8] = acc;
        }
    }

    // ---- level 3: bits 2,3 ----
    C2 S3[2][3];
    #pragma unroll
    for (int t1 = 0; t1 < 2; ++t1) {
        #pragma unroll
        for (int c8 = 0; c8 < 3; ++c8) {
            C2 acc = C2{0.0f, 0.0f};
            #pragma unroll
            for (int c3 = 0; c3 < 3; ++c3) {
                const int a3 = A[c3], b3 = B[c3];
                C2 v = cmul(K[3][c3], F[2][t1][b3]);
                v = cmul(v, F[3][t1 ^ a3][b3]);
                v = cmul(v, S5[t1 ^ a3][c8]);
                acc = cadd(acc, v);
            }
            S3[t1][c8] = acc;
        }
    }

    // ---- level 1: bits 0,1 ----
    C2 S1[3];
    #pragma unroll
    for (int c8 = 0; c8 < 3; ++c8) {
        const int a8 = A[c8];
        C2 acc = C2{0.0f, 0.0f};
        #pragma unroll
        for (int c1 = 0; c1 < 3; ++c1) {
            const int a1 = A[c1], b1 = B[c1];
            C2 v = cmul(K[4][c1], F[0][a8][b1]);
            v = cmul(v, F[1][a8 ^ a1][b1]);
            v = cmul(v, S3[a8 ^ a1][c8]);
            acc = cadd(acc, v);
        }
        S1[c8] = acc;
    }

    // ---- close over c8; every term is real -> take Re ----
    float E = 0.0f;
    #pragma unroll
    for (int c8 = 0; c8 < 3; ++c8)
        E += K[0][c8].r * S1[c8].r - K[0][c8].i * S1[c8].i;

    out[n] = E;
}

extern "C" void kernel_launch(void* const* d_in, const int* in_sizes, int n_in,
                              void* d_out, int out_size, void* d_ws, size_t ws_size,
                              hipStream_t stream) {
    const float* x = (const float*)d_in[0];   // (8,1,64,64) float32
    const float* w = (const float*)d_in[1];   // (2,9,3) float32
    float* out = (float*)d_out;               // 32768 float32
    const int nsamples = out_size;
    const int blocks = (nsamples + 63) >> 6;
    qsim_kernel<<<blocks, 64, 0, stream>>>(x, w, out, nsamples);
}

// Round 2
// 9.403 us; speedup vs baseline: 4.3100x; 1.0467x over previous
//
#include <hip/hip_runtime.h>

// Closed-form Pauli contraction, v2: Bloch-direct embedding + 2-wave DP split.
//
// Frame (inherited, harness-verified): after folding layer-1 CNOTs into a
// GF(2) index remap, |psi> is a PRODUCT state over 9 physical bits (bit m
// holds qubit q = 8-m), and the conjugated observable is
//   O = prod_{p in {8,7,5,3,1}} h^(p),
//   h^(p) = al_p Z_{u_p} + br_p X_{w_p} + i bi_p Z_{u_p} X_{w_p}
// with u_p . w_q = delta_pq. Expanding into 3^5 = 243 Pauli terms Z_U X_W
// (trit c_p: 0->Z coeff al, 1->X coeff br, 2->ZX coeff i*bi), the
// product-state expectation factors per bit: <Z^u X^w> = 1 / z / x / i*y.
// Per-bit (U_m, W_m) staircase in the choice bits:
//   m=0:(a8,b1) m=1:(t1,b1) m=2:(t1,b3) m=3:(t3,b3) m=4:(t3,b5)
//   m=5:(t5,b5) m=6:(t5,b7) m=7:(t5^a7,b7^b8) m=8:(t5^a8^a7,b8)
//   t1=a8^a1, t3=t1^a3, t5=t3^a5  ->  4-level DP with state (t, c8).
//
// v2 changes vs the 9.8 us version:
//  (1) Bloch-direct: Bloch(RX(a)|0>) = cos(a) z^ - sin(a) y^, and
//      Bloch(U psi) = R(U) Bloch(psi). Precompute per qubit the SO(3)
//      columns Cz = R z^, Cy = R y^ once per block (via Bloch(U|0>) and
//      Bloch(U|y+>), |y+> = (|0>+i|1>)/sqrt2 -- first-principles, no
//      formula recall). Per thread per bit: 1 sincos + 6 FMA. Kills the
//      2-vector build + quadratic Bloch extraction (~110 VALU + 20 LDS).
//  (2) 2-wave split: 128-thread blocks, both waves own the same 64 samples.
//      Wave 0 evaluates the c8=0 DP slice (1/3 of terms), wave 1 the
//      c8 in {1,2} slice (2/3); partials combined through LDS. Split is
//      wave-uniform (compile-time template per wave) -> no divergence;
//      wave count 512 -> 1024 covers all 1024 SIMDs.

#if defined(__clang__)
#pragma float_control(precise, off)   // fold the structural 0/1 components
#endif

struct C2 { float r, i; };
__device__ __forceinline__ C2 cmul(C2 a, C2 b) {
    return C2{a.r * b.r - a.i * b.i, a.r * b.i + a.i * b.r};
}
__device__ __forceinline__ C2 cadd(C2 a, C2 b) { return C2{a.r + b.r, a.i + b.i}; }

// DP over the c8-slice [C8BASE, C8BASE+NC8). Returns the partial expectation.
template<int C8BASE, int NC8>
__device__ __forceinline__ float dp_eval(const float (&Zb)[9], const float (&Xb)[9],
                                         const float (&Yb)[9], const float (&hm)[5][3]) {
    // per-bit complex Pauli factors F[m][U][W]; structural zeros fold at -O3
    C2 F[9][2][2];
    #pragma unroll
    for (int m = 0; m < 9; ++m) {
        F[m][0][0] = C2{1.0f, 0.0f};
        F[m][1][0] = C2{Zb[m], 0.0f};
        F[m][0][1] = C2{Xb[m], 0.0f};
        F[m][1][1] = C2{0.0f, Yb[m]};
    }
    // choice coefficients: slot 0=p8, 1=p7, 2=p5, 3=p3, 4=p1
    C2 K[5][3];
    #pragma unroll
    for (int i = 0; i < 5; ++i) {
        K[i][0] = C2{hm[i][0], 0.0f};   // alpha  (Z)
        K[i][1] = C2{hm[i][1], 0.0f};   // br     (X)
        K[i][2] = C2{0.0f, hm[i][2]};   // i*bi   (ZX)
    }
    const int A[3] = {1, 0, 1};
    const int B[3] = {0, 1, 1};

    // ---- level 7: bits 6,7,8 ----
    C2 S7[2][NC8];
    #pragma unroll
    for (int t5 = 0; t5 < 2; ++t5) {
        #pragma unroll
        for (int c8i = 0; c8i < NC8; ++c8i) {
            const int c8 = C8BASE + c8i;
            const int a8 = A[c8], b8 = B[c8];
            C2 acc = C2{0.0f, 0.0f};
            #pragma unroll
            for (int c7 = 0; c7 < 3; ++c7) {
                const int a7 = A[c7], b7 = B[c7];
                C2 v = cmul(K[1][c7], F[6][t5][b7]);
                v = cmul(v, F[7][t5 ^ a7][b7 ^ b8]);
                v = cmul(v, F[8][t5 ^ a8 ^ a7][b8]);
                acc = cadd(acc, v);
            }
            S7[t5][c8i] = acc;
        }
    }
    // ---- level 5: bits 4,5 ----
    C2 S5[2][NC8];
    #pragma unroll
    for (int t3 = 0; t3 < 2; ++t3) {
        #pragma unroll
        for (int c8i = 0; c8i < NC8; ++c8i) {
            C2 acc = C2{0.0f, 0.0f};
            #pragma unroll
            for (int c5 = 0; c5 < 3; ++c5) {
                const int a5 = A[c5], b5 = B[c5];
                C2 v = cmul(K[2][c5], F[4][t3][b5]);
                v = cmul(v, F[5][t3 ^ a5][b5]);
                v = cmul(v, S7[t3 ^ a5][c8i]);
                acc = cadd(acc, v);
            }
            S5[t3][c8i] = acc;
        }
    }
    // ---- level 3: bits 2,3 ----
    C2 S3[2][NC8];
    #pragma unroll
    for (int t1 = 0; t1 < 2; ++t1) {
        #pragma unroll
        for (int c8i = 0; c8i < NC8; ++c8i) {
            C2 acc = C2{0.0f, 0.0f};
            #pragma unroll
            for (int c3 = 0; c3 < 3; ++c3) {
                const int a3 = A[c3], b3 = B[c3];
                C2 v = cmul(K[3][c3], F[2][t1][b3]);
                v = cmul(v, F[3][t1 ^ a3][b3]);
                v = cmul(v, S5[t1 ^ a3][c8i]);
                acc = cadd(acc, v);
            }
            S3[t1][c8i] = acc;
        }
    }
    // ---- level 1: bits 0,1, then close over c8 (every term is real) ----
    float E = 0.0f;
    #pragma unroll
    for (int c8i = 0; c8i < NC8; ++c8i) {
        const int c8 = C8BASE + c8i;
        const int a8 = A[c8];
        C2 acc = C2{0.0f, 0.0f};
        #pragma unroll
        for (int c1 = 0; c1 < 3; ++c1) {
            const int a1 = A[c1], b1 = B[c1];
            C2 v = cmul(K[4][c1], F[0][a8][b1]);
            v = cmul(v, F[1][a8 ^ a1][b1]);
            v = cmul(v, S3[a8 ^ a1][c8i]);
            acc = cadd(acc, v);
        }
        E += K[0][c8].r * acc.r - K[0][c8].i * acc.i;
    }
    return E;
}

__global__ __launch_bounds__(128) void qsim_kernel(const float* __restrict__ x,
                                                   const float* __restrict__ w,
                                                   float* __restrict__ out,
                                                   int nsamples) {
    __shared__ float cb[9][6];   // per qubit: {Cz_z, Cy_z, Cz_x, Cy_x, Cz_y, Cy_y}
    __shared__ float hm[5][3];   // h params for p = 8,7,5,3,1: {alpha, beta_r, beta_i}
    __shared__ float part[64];   // wave-1 partials
    const int tid = threadIdx.x;
    if (tid < 9) {
        const int q = tid;
        const float phi = w[q * 3 + 0], theta = w[q * 3 + 1], omega = w[q * 3 + 2];
        float st, ct, sp, cp, sm, cm;
        __sincosf(0.5f * theta, &st, &ct);
        __sincosf(0.5f * (phi + omega), &sp, &cp);
        __sincosf(0.5f * (phi - omega), &sm, &cm);
        const float m00r =  cp * ct, m00i = -sp * ct;
        const float m01r = -cm * st, m01i = -sm * st;
        const float m10r =  cm * st, m10i = -sm * st;
        const float m11r =  cp * ct, m11i =  sp * ct;
        // Cz = Bloch(U|0>) = Bloch((m00, m10)), components (z, x, y)
        cb[q][0] = (m00r * m00r + m00i * m00i) - (m10r * m10r + m10i * m10i);
        cb[q][2] = 2.0f * (m00r * m10r + m00i * m10i);
        cb[q][4] = 2.0f * (m00r * m10i - m00i * m10r);
        // Cy = Bloch(U|y+>), |y+> = (|0>+i|1>)/sqrt2 -> u = (m00+i*m01, m10+i*m11)/sqrt2
        // (1/sqrt2 factors folded: |.|^2 terms get 1/2, cross terms' 2x cancels)
        const float u0r = m00r - m01i, u0i = m00i + m01r;
        const float u1r = m10r - m11i, u1i = m10i + m11r;
        cb[q][1] = 0.5f * ((u0r * u0r + u0i * u0i) - (u1r * u1r + u1i * u1i));
        cb[q][3] = (u0r * u1r + u0i * u1i);
        cb[q][5] = (u0r * u1i - u0i * u1r);
    } else if (tid >= 16 && tid < 21) {
        const int i = tid - 16;
        const int qs[5] = {0, 1, 3, 5, 7};  // wire q; logical p = 8,7,5,3,1
        const int q = qs[i];
        const float phi = w[27 + q * 3 + 0], theta = w[27 + q * 3 + 1];
        float stt, ctt, sf, cf;
        __sincosf(theta, &stt, &ctt);
        __sincosf(phi, &sf, &cf);
        hm[i][0] = ctt;          // alpha = cos(theta)
        hm[i][1] = -stt * cf;    // beta  = -sin(theta) e^{i phi}
        hm[i][2] = -stt * sf;
    }
    __syncthreads();

    const int lane = tid & 63;
    const int half = tid >> 6;               // wave id in block (uniform per wave)
    const int n = (blockIdx.x << 6) + lane;  // both waves own the same 64 samples

    float E = 0.0f;
    if (n < nsamples) {
        const int b  = n >> 12;
        const int i0 = (n >> 6) & 63;
        const int j0 = n & 63;               // lane == column -> coalesced loads

        // Bloch components per physical bit m (qubit q = 8 - m):
        // Bloch(U_q RX(a)|0>) = cos(a) * Cz_q - sin(a) * Cy_q
        float Zb[9], Xb[9], Yb[9];
        #pragma unroll
        for (int ki = 0; ki < 3; ++ki) {
            #pragma unroll
            for (int kj = 0; kj < 3; ++kj) {
                const int q = ki * 3 + kj;
                const int m = 8 - q;
                const int ii = i0 + ki - 1, jj = j0 + kj - 1;
                float a = 0.0f;
                if (ii >= 0 && ii < 64 && jj >= 0 && jj < 64)
                    a = x[(b << 12) + (ii << 6) + jj];
                float sa, ca;
                __sincosf(a, &sa, &ca);
                Zb[m] = ca * cb[q][0] - sa * cb[q][1];
                Xb[m] = ca * cb[q][2] - sa * cb[q][3];
                Yb[m] = ca * cb[q][4] - sa * cb[q][5];
            }
        }
        if (half == 0) E = dp_eval<0, 1>(Zb, Xb, Yb, hm);  // c8 = 0 slice
        else           E = dp_eval<1, 2>(Zb, Xb, Yb, hm);  // c8 in {1,2} slice
    }
    if (half) part[lane] = E;
    __syncthreads();
    if (!half && n < nsamples) out[n] = E + part[lane];
}

extern "C" void kernel_launch(void* const* d_in, const int* in_sizes, int n_in,
                              void* d_out, int out_size, void* d_ws, size_t ws_size,
                              hipStream_t stream) {
    const float* x = (const float*)d_in[0];   // (8,1,64,64) float32
    const float* w = (const float*)d_in[1];   // (2,9,3) float32
    float* out = (float*)d_out;               // 32768 float32
    const int nsamples = out_size;
    const int blocks = (nsamples + 63) >> 6;  // 64 samples per 128-thread block
    qsim_kernel<<<blocks, 128, 0, stream>>>(x, w, out, nsamples);
}